// Round 4
// baseline (1244.945 us; speedup 1.0000x reference)
//
#include <hip/hip_runtime.h>
#include <hip/hip_bf16.h>

#define LEAKY 0.2f
#define EPS_GN 1e-5f
#define NBUCKET 2048

typedef unsigned int uint;

// ---------------- bf16 helpers (storage only; compute fp32) ----------------

__device__ inline float4 bf4(uint2 u) {
    union { uint u; float f; } a, b, c, d;
    a.u = u.x << 16; b.u = u.x & 0xFFFF0000u;
    c.u = u.y << 16; d.u = u.y & 0xFFFF0000u;
    return make_float4(a.f, b.f, c.f, d.f);
}

__device__ inline uint pack_bf2(float lo, float hi) {
    union { float f; uint u; } x, y; x.f = lo; y.f = hi;
    uint ra = x.u + 0x7FFFu + ((x.u >> 16) & 1u);
    uint rb = y.u + 0x7FFFu + ((y.u >> 16) & 1u);
    return (ra >> 16) | (rb & 0xFFFF0000u);
}

// ---------------- CSR build ----------------

__global__ void zero_int_kernel(int* __restrict__ p, int n) {
    int i = blockIdx.x * blockDim.x + threadIdx.x;
    if (i < n) p[i] = 0;
}

__global__ void hist_kernel(const int* __restrict__ dst, int* __restrict__ deg, int E_, int Etot_) {
    int i = blockIdx.x * blockDim.x + threadIdx.x;
    if (i >= Etot_) return;
    int d = (i < E_) ? dst[i] : (i - E_);
    atomicAdd(&deg[d], 1);
}

__global__ void scan1_kernel(const int* __restrict__ deg, int* __restrict__ bsum, int nN) {
    __shared__ int sd[256];
    int i = blockIdx.x * 256 + threadIdx.x;
    sd[threadIdx.x] = (i < nN) ? deg[i] : 0;
    __syncthreads();
    for (int off = 128; off > 0; off >>= 1) {
        if (threadIdx.x < off) sd[threadIdx.x] += sd[threadIdx.x + off];
        __syncthreads();
    }
    if (threadIdx.x == 0) bsum[blockIdx.x] = sd[0];
}

__global__ void scan2_kernel(const int* __restrict__ bsum, int* __restrict__ bofs, int nb,
                             int* __restrict__ rowstart, int nN) {
    if (threadIdx.x == 0 && blockIdx.x == 0) {
        int run = 0;
        for (int i = 0; i < nb; ++i) { bofs[i] = run; run += bsum[i]; }
        rowstart[nN] = run;
    }
}

__global__ void scan3_kernel(const int* __restrict__ deg, const int* __restrict__ bofs,
                             int* __restrict__ rowstart, int nN) {
    __shared__ int sd[256];
    int i = blockIdx.x * 256 + threadIdx.x;
    int v = (i < nN) ? deg[i] : 0;
    sd[threadIdx.x] = v;
    __syncthreads();
    for (int off = 1; off < 256; off <<= 1) {
        int t = (threadIdx.x >= off) ? sd[threadIdx.x - off] : 0;
        __syncthreads();
        sd[threadIdx.x] += t;
        __syncthreads();
    }
    if (i < nN) rowstart[i] = bofs[blockIdx.x] + sd[threadIdx.x] - v;
}

__global__ void fill_kernel(const int* __restrict__ srcs, const int* __restrict__ dsts,
                            const int* __restrict__ rowstart, int* __restrict__ cursor,
                            int* __restrict__ csr, int E_, int Etot_) {
    int i = blockIdx.x * blockDim.x + threadIdx.x;
    if (i >= Etot_) return;
    int s, d;
    if (i < E_) { s = srcs[i]; d = dsts[i]; } else { s = i - E_; d = s; }
    int pos = rowstart[d] + atomicAdd(&cursor[d], 1);
    csr[pos] = s;
}

__global__ void goff_kernel(const int* __restrict__ batch, int* __restrict__ goff, int nN, int nG) {
    int g = blockIdx.x * blockDim.x + threadIdx.x;
    if (g > nG) return;
    if (g == nG) { goff[g] = nN; return; }
    int lo = 0, hi = nN;
    while (lo < hi) { int mid = (lo + hi) >> 1; if (batch[mid] < g) lo = mid + 1; else hi = mid; }
    goff[g] = lo;
}

// ---------------- degree bucket sort (descending degree) ----------------

__global__ void bucket_hist_kernel(const int* __restrict__ deg, int* __restrict__ bcount, int nN) {
    int i = blockIdx.x * blockDim.x + threadIdx.x;
    if (i >= nN) return;
    int d = deg[i]; d = d < NBUCKET - 1 ? d : NBUCKET - 1;
    atomicAdd(&bcount[NBUCKET - 1 - d], 1);
}

__global__ void bucket_scan_kernel(const int* __restrict__ bcount, int* __restrict__ bstart) {
    __shared__ int part[256];
    int tid = threadIdx.x;
    int base = tid * 8;
    int v[8];
    int s = 0;
#pragma unroll
    for (int k = 0; k < 8; ++k) { v[k] = bcount[base + k]; s += v[k]; }
    part[tid] = s;
    __syncthreads();
    for (int off = 1; off < 256; off <<= 1) {
        int t = (tid >= off) ? part[tid - off] : 0;
        __syncthreads();
        part[tid] += t;
        __syncthreads();
    }
    int run = part[tid] - s;
#pragma unroll
    for (int k = 0; k < 8; ++k) { bstart[base + k] = run; run += v[k]; }
}

__global__ void bucket_scatter_kernel(const int* __restrict__ deg, const int* __restrict__ bstart,
                                      int* __restrict__ bcur, int* __restrict__ perm, int nN) {
    int i = blockIdx.x * blockDim.x + threadIdx.x;
    if (i >= nN) return;
    int d = deg[i]; d = d < NBUCKET - 1 ? d : NBUCKET - 1;
    int b = NBUCKET - 1 - d;
    int pos = bstart[b] + atomicAdd(&bcur[b], 1);
    perm[pos] = i;
}

// ---------------- GEMM: xl = f(x)@Wl, xr = f(x)@Wr (K=64), bf16 out ----------------

template <int D, bool NORM>
__global__ void gemm2_kernel(const float* __restrict__ x, const float* __restrict__ Wl,
                             const float* __restrict__ Wr, unsigned short* __restrict__ xl,
                             unsigned short* __restrict__ xr, int nN,
                             const float* __restrict__ param, const int* __restrict__ batch) {
    constexpr int TPN = D / 16;
    constexpr int NPB = 256 / TPN;
    __shared__ float w_s[64 * D];
    __shared__ float x_s[NPB][65];
    int tid = threadIdx.x;
    int node0 = blockIdx.x * NPB;
    for (int i = tid; i < NPB * 64; i += 256) {
        int r = i >> 6, c = i & 63;
        int n = node0 + r;
        float v = 0.f;
        if (n < nN) {
            v = x[(size_t)n * 64 + c];
            if constexpr (NORM) {
                int g = batch[n];
                float sc = param[(size_t)g * 128 + c];
                float sh = param[(size_t)g * 128 + 64 + c];
                v = fmaxf(fmaf(sc, v, sh), 0.f);
            }
        }
        x_s[r][c] = v;
    }
    int local = tid / TPN, j0 = (tid % TPN) * 16;
    int n = node0 + local;
    float acc[16];

    for (int i = tid; i < 64 * D; i += 256) w_s[i] = Wl[i];
    __syncthreads();
#pragma unroll
    for (int j = 0; j < 16; ++j) acc[j] = 0.f;
    for (int k = 0; k < 64; ++k) {
        float xv = x_s[local][k];
        const float* wrow = &w_s[k * D + j0];
#pragma unroll
        for (int j = 0; j < 16; ++j) acc[j] = fmaf(xv, wrow[j], acc[j]);
    }
    if (n < nN) {
        uint4* dst = (uint4*)(xl + (size_t)n * D + j0);
        dst[0] = make_uint4(pack_bf2(acc[0], acc[1]), pack_bf2(acc[2], acc[3]),
                            pack_bf2(acc[4], acc[5]), pack_bf2(acc[6], acc[7]));
        dst[1] = make_uint4(pack_bf2(acc[8], acc[9]), pack_bf2(acc[10], acc[11]),
                            pack_bf2(acc[12], acc[13]), pack_bf2(acc[14], acc[15]));
    }
    __syncthreads();

    for (int i = tid; i < 64 * D; i += 256) w_s[i] = Wr[i];
    __syncthreads();
#pragma unroll
    for (int j = 0; j < 16; ++j) acc[j] = 0.f;
    for (int k = 0; k < 64; ++k) {
        float xv = x_s[local][k];
        const float* wrow = &w_s[k * D + j0];
#pragma unroll
        for (int j = 0; j < 16; ++j) acc[j] = fmaf(xv, wrow[j], acc[j]);
    }
    if (n < nN) {
        uint4* dst = (uint4*)(xr + (size_t)n * D + j0);
        dst[0] = make_uint4(pack_bf2(acc[0], acc[1]), pack_bf2(acc[2], acc[3]),
                            pack_bf2(acc[4], acc[5]), pack_bf2(acc[6], acc[7]));
        dst[1] = make_uint4(pack_bf2(acc[8], acc[9]), pack_bf2(acc[10], acc[11]),
                            pack_bf2(acc[12], acc[13]), pack_bf2(acc[14], acc[15]));
    }
}

// ---------------- Aggregate layer 1-2: D=64, H=4, C=16, concat ----------------
// 16-lane group per node (4 nodes/wave), degree-sorted perm, no-max softmax.

__global__ void agg64_kernel(const unsigned short* __restrict__ xl, const unsigned short* __restrict__ xr,
                             const int* __restrict__ rowstart, const int* __restrict__ csr,
                             const int* __restrict__ perm,
                             const float* __restrict__ att, const float* __restrict__ bias,
                             float* __restrict__ out, int nN) {
    int tid = threadIdx.x;
    int lane = tid & 63;
    int c4 = lane & 15;
    int gid = blockIdx.x * 16 + (tid >> 6) * 4 + (lane >> 4);
    if (gid >= nN) return;
    int node = perm[gid];
    const uint2* xl2 = (const uint2*)xl;
    const float LOG2E = 1.4426950408889634f;
    float4 attv = ((const float4*)att)[c4];
    attv.x *= LOG2E; attv.y *= LOG2E; attv.z *= LOG2E; attv.w *= LOG2E;
    float4 xrv = bf4(((const uint2*)xr)[(size_t)node * 16 + c4]);
    int rs = rowstart[node], re = rowstart[node + 1];
    float den = 0.f;
    float4 acc = make_float4(0.f, 0.f, 0.f, 0.f);
    int s = csr[rs];
    uint2 xv = xl2[(size_t)s * 16 + c4];
    for (int i = rs; i < re; ++i) {
        float4 cur = bf4(xv);
        int inext = (i + 1 < re) ? i + 1 : re - 1;
        s = csr[inext];
        xv = xl2[(size_t)s * 16 + c4];   // prefetch next edge
        float4 mm;
        mm.x = cur.x + xrv.x; mm.y = cur.y + xrv.y;
        mm.z = cur.z + xrv.z; mm.w = cur.w + xrv.w;
        mm.x = fmaxf(mm.x, LEAKY * mm.x);
        mm.y = fmaxf(mm.y, LEAKY * mm.y);
        mm.z = fmaxf(mm.z, LEAKY * mm.z);
        mm.w = fmaxf(mm.w, LEAKY * mm.w);
        float p = mm.x * attv.x;
        p = fmaf(mm.y, attv.y, p);
        p = fmaf(mm.z, attv.z, p);
        p = fmaf(mm.w, attv.w, p);
        p += __shfl_xor(p, 1);
        p += __shfl_xor(p, 2);
        float w = exp2f(p);
        den += w;
        acc.x = fmaf(w, cur.x, acc.x);
        acc.y = fmaf(w, cur.y, acc.y);
        acc.z = fmaf(w, cur.z, acc.z);
        acc.w = fmaf(w, cur.w, acc.w);
    }
    float4 bv = ((const float4*)bias)[c4];
    float inv = 1.f / den;
    float4 r;
    r.x = fmaf(acc.x, inv, bv.x);
    r.y = fmaf(acc.y, inv, bv.y);
    r.z = fmaf(acc.z, inv, bv.z);
    r.w = fmaf(acc.w, inv, bv.w);
    ((float4*)out)[(size_t)node * 16 + c4] = r;
}

// ---------------- Aggregate layer 3: D=128, H=4, C=32, head-mean ----------------
// 32-lane group per node (2 nodes/wave).

__global__ void agg128_mean_kernel(const unsigned short* __restrict__ xl, const unsigned short* __restrict__ xr,
                                   const int* __restrict__ rowstart, const int* __restrict__ csr,
                                   const int* __restrict__ perm,
                                   const float* __restrict__ att, const float* __restrict__ bias,
                                   float* __restrict__ out, int nN) {
    int tid = threadIdx.x;
    int lane = tid & 63;
    int c4 = lane & 31;
    int gid = blockIdx.x * 8 + (tid >> 6) * 2 + (lane >> 5);
    if (gid >= nN) return;
    int node = perm[gid];
    const uint2* xl2 = (const uint2*)xl;
    const float LOG2E = 1.4426950408889634f;
    float4 attv = ((const float4*)att)[c4];
    attv.x *= LOG2E; attv.y *= LOG2E; attv.z *= LOG2E; attv.w *= LOG2E;
    float4 xrv = bf4(((const uint2*)xr)[(size_t)node * 32 + c4]);
    int rs = rowstart[node], re = rowstart[node + 1];
    float den = 0.f;
    float4 acc = make_float4(0.f, 0.f, 0.f, 0.f);
    int s = csr[rs];
    uint2 xv = xl2[(size_t)s * 32 + c4];
    for (int i = rs; i < re; ++i) {
        float4 cur = bf4(xv);
        int inext = (i + 1 < re) ? i + 1 : re - 1;
        s = csr[inext];
        xv = xl2[(size_t)s * 32 + c4];   // prefetch next edge
        float4 mm;
        mm.x = cur.x + xrv.x; mm.y = cur.y + xrv.y;
        mm.z = cur.z + xrv.z; mm.w = cur.w + xrv.w;
        mm.x = fmaxf(mm.x, LEAKY * mm.x);
        mm.y = fmaxf(mm.y, LEAKY * mm.y);
        mm.z = fmaxf(mm.z, LEAKY * mm.z);
        mm.w = fmaxf(mm.w, LEAKY * mm.w);
        float p = mm.x * attv.x;
        p = fmaf(mm.y, attv.y, p);
        p = fmaf(mm.z, attv.z, p);
        p = fmaf(mm.w, attv.w, p);
        p += __shfl_xor(p, 1);
        p += __shfl_xor(p, 2);
        p += __shfl_xor(p, 4);
        float w = exp2f(p);
        den += w;
        acc.x = fmaf(w, cur.x, acc.x);
        acc.y = fmaf(w, cur.y, acc.y);
        acc.z = fmaf(w, cur.z, acc.z);
        acc.w = fmaf(w, cur.w, acc.w);
    }
    float inv = 1.f / den;
    float4 r;
    r.x = acc.x * inv; r.y = acc.y * inv; r.z = acc.z * inv; r.w = acc.w * inv;
    // head mean: sum lanes differing in c4 bits 3,4
    r.x += __shfl_xor(r.x, 8);  r.y += __shfl_xor(r.y, 8);
    r.z += __shfl_xor(r.z, 8);  r.w += __shfl_xor(r.w, 8);
    r.x += __shfl_xor(r.x, 16); r.y += __shfl_xor(r.y, 16);
    r.z += __shfl_xor(r.z, 16); r.w += __shfl_xor(r.w, 16);
    if (c4 < 8) {
        float4 bv = ((const float4*)bias)[c4];
        float4 o;
        o.x = r.x * 0.25f + bv.x;
        o.y = r.y * 0.25f + bv.y;
        o.z = r.z * 0.25f + bv.z;
        o.w = r.w * 0.25f + bv.w;
        ((float4*)out)[(size_t)node * 8 + c4] = o;
    }
}

// ---------------- GraphNorm stats / finalize ----------------

template <int D>
__global__ void gnorm_stats_kernel(const float* __restrict__ in, const int* __restrict__ goff,
                                   float* __restrict__ stats, int SPLIT) {
    int g = blockIdx.x / SPLIT, part = blockIdx.x % SPLIT;
    int start = goff[g], end = goff[g + 1];
    constexpr int RPB = 256 / D;
    int tid = threadIdx.x;
    int c = tid % D, sub = tid / D;
    float s1 = 0.f, s2 = 0.f;
    for (int n = start + part * RPB + sub; n < end; n += SPLIT * RPB) {
        float v = in[(size_t)n * D + c];
        s1 += v; s2 += v * v;
    }
    __shared__ float l1[256], l2[256];
    l1[tid] = s1; l2[tid] = s2;
    __syncthreads();
    if (tid < D) {
        for (int s = 1; s < RPB; ++s) { s1 += l1[s * D + tid]; s2 += l2[s * D + tid]; }
        atomicAdd(&stats[(size_t)g * 2 * D + tid], s1);
        atomicAdd(&stats[(size_t)g * 2 * D + D + tid], s2);
    }
}

template <int D>
__global__ void gnorm_finalize_kernel(const float* __restrict__ stats, const int* __restrict__ goff,
                                      const float* __restrict__ w, const float* __restrict__ b,
                                      const float* __restrict__ a, float* __restrict__ param) {
    int g = blockIdx.x, c = threadIdx.x;
    if (c >= D) return;
    int cn = goff[g + 1] - goff[g];
    float cnt = (float)(cn > 1 ? cn : 1);
    float S1 = stats[(size_t)g * 2 * D + c], S2 = stats[(size_t)g * 2 * D + D + c];
    float mu = S1 / cnt;
    float am = a[c] * mu;
    float var = S2 / cnt - 2.f * am * mu + am * am;
    float sc = w[c] * rsqrtf(var + EPS_GN);
    param[(size_t)g * 2 * D + c] = sc;
    param[(size_t)g * 2 * D + D + c] = b[c] - sc * am;
}

// ---------------- layer-3 tail ----------------

__global__ void pool3_kernel(const float* __restrict__ in, const int* __restrict__ goff,
                             const float* __restrict__ param, float* __restrict__ pooled, int SPLIT) {
    int g = blockIdx.x / SPLIT, part = blockIdx.x % SPLIT;
    int start = goff[g], end = goff[g + 1];
    int tid = threadIdx.x;
    int c = tid & 31, sub = tid >> 5;
    float sc = param[(size_t)g * 64 + c], sh = param[(size_t)g * 64 + 32 + c];
    float s = 0.f;
    for (int n = start + part * 8 + sub; n < end; n += SPLIT * 8)
        s += fmaxf(fmaf(sc, in[(size_t)n * 32 + c], sh), 0.f);
    __shared__ float l[256];
    l[tid] = s;
    __syncthreads();
    if (tid < 32) {
        for (int q = 1; q < 8; ++q) s += l[q * 32 + tid];
        atomicAdd(&pooled[(size_t)g * 32 + tid], s);
    }
}

__global__ void lin_kernel(const float* __restrict__ pooled, const int* __restrict__ goff,
                           const float* __restrict__ Wlin, const float* __restrict__ blin,
                           float* __restrict__ out, int nG) {
    int idx = blockIdx.x * blockDim.x + threadIdx.x;
    if (idx >= nG * 2) return;
    int g = idx >> 1, o = idx & 1;
    int cn = goff[g + 1] - goff[g];
    float inv = 1.f / (float)(cn > 1 ? cn : 1);
    float acc = blin[o];
    for (int c = 0; c < 32; ++c) acc = fmaf(pooled[(size_t)g * 32 + c] * inv, Wlin[c * 2 + o], acc);
    out[idx] = acc;
}

// ---------------- launch ----------------

extern "C" void kernel_launch(void* const* d_in, const int* in_sizes, int n_in,
                              void* d_out, int out_size, void* d_ws, size_t ws_size,
                              hipStream_t stream) {
    const float* x    = (const float*)d_in[0];
    const int*  eidx  = (const int*)d_in[1];
    const int*  batch = (const int*)d_in[2];
    const float* Wl1 = (const float*)d_in[3];
    const float* Wr1 = (const float*)d_in[4];
    const float* att1 = (const float*)d_in[5];
    const float* b1 = (const float*)d_in[6];
    const float* g1w = (const float*)d_in[7];
    const float* g1b = (const float*)d_in[8];
    const float* g1a = (const float*)d_in[9];
    const float* Wl2 = (const float*)d_in[10];
    const float* Wr2 = (const float*)d_in[11];
    const float* att2 = (const float*)d_in[12];
    const float* b2 = (const float*)d_in[13];
    const float* g2w = (const float*)d_in[14];
    const float* g2b = (const float*)d_in[15];
    const float* g2a = (const float*)d_in[16];
    const float* Wl3 = (const float*)d_in[17];
    const float* Wr3 = (const float*)d_in[18];
    const float* att3 = (const float*)d_in[19];
    const float* b3 = (const float*)d_in[20];
    const float* g3w = (const float*)d_in[21];
    const float* g3b = (const float*)d_in[22];
    const float* g3a = (const float*)d_in[23];
    const float* Wlin = (const float*)d_in[24];
    const float* blin = (const float*)d_in[25];
    float* outp = (float*)d_out;

    const int N = in_sizes[0] / 64;
    const int E = in_sizes[1] / 2;
    const int Etot = N + E;
    const int G = out_size / 2;
    const int NB = (N + 255) / 256;
    const int SPLIT = 16;

    unsigned short* xlb = (unsigned short*)d_ws;           // N*128 bf16
    unsigned short* xrb = xlb + (size_t)N * 128;           // N*128 bf16
    float* agg   = (float*)(xrb + (size_t)N * 128);        // N*64 f32
    float* stats = agg + (size_t)N * 64;
    float* stats1 = stats;
    float* stats2 = stats1 + (size_t)G * 128;
    float* stats3 = stats2 + (size_t)G * 128;
    float* pooled = stats3 + (size_t)G * 64;
    float* param  = pooled + (size_t)G * 32;               // G*128, reused per layer
    int* deg      = (int*)(param + (size_t)G * 128);
    int* cursor   = deg + N;
    int* rowstart = cursor + N;
    int* csr      = rowstart + (N + 1);
    int* bsum     = csr + Etot;
    int* bofs     = bsum + NB;
    int* goff     = bofs + NB;
    int* bcount   = goff + (G + 1);
    int* bcur     = bcount + NBUCKET;
    int* bstart   = bcur + NBUCKET;
    int* perm     = bstart + NBUCKET;

    const int* src_idx = eidx;
    const int* dst_idx = eidx + E;

    zero_int_kernel<<<(2 * N + 255) / 256, 256, 0, stream>>>(deg, 2 * N);
    zero_int_kernel<<<(G * 352 + 255) / 256, 256, 0, stream>>>((int*)stats, G * 352);
    zero_int_kernel<<<(2 * NBUCKET + 255) / 256, 256, 0, stream>>>(bcount, 2 * NBUCKET);

    hist_kernel<<<(Etot + 255) / 256, 256, 0, stream>>>(dst_idx, deg, E, Etot);
    scan1_kernel<<<NB, 256, 0, stream>>>(deg, bsum, N);
    scan2_kernel<<<1, 64, 0, stream>>>(bsum, bofs, NB, rowstart, N);
    scan3_kernel<<<NB, 256, 0, stream>>>(deg, bofs, rowstart, N);
    fill_kernel<<<(Etot + 255) / 256, 256, 0, stream>>>(src_idx, dst_idx, rowstart, cursor, csr, E, Etot);
    goff_kernel<<<1, 128, 0, stream>>>(batch, goff, N, G);

    // degree-descending permutation
    bucket_hist_kernel<<<NB, 256, 0, stream>>>(deg, bcount, N);
    bucket_scan_kernel<<<1, 256, 0, stream>>>(bcount, bstart);
    bucket_scatter_kernel<<<NB, 256, 0, stream>>>(deg, bstart, bcur, perm, N);

    dim3 blk(256);
    int agg64Grid = (N + 15) / 16;
    int agg128Grid = (N + 7) / 8;

    // Layer 1
    gemm2_kernel<64, false><<<(N + 63) / 64, blk, 0, stream>>>(x, Wl1, Wr1, xlb, xrb, N, nullptr, nullptr);
    agg64_kernel<<<agg64Grid, blk, 0, stream>>>(xlb, xrb, rowstart, csr, perm, att1, b1, agg, N);
    gnorm_stats_kernel<64><<<G * SPLIT, blk, 0, stream>>>(agg, goff, stats1, SPLIT);
    gnorm_finalize_kernel<64><<<G, 64, 0, stream>>>(stats1, goff, g1w, g1b, g1a, param);

    // Layer 2 (norm of layer 1 fused into GEMM staging)
    gemm2_kernel<64, true><<<(N + 63) / 64, blk, 0, stream>>>(agg, Wl2, Wr2, xlb, xrb, N, param, batch);
    agg64_kernel<<<agg64Grid, blk, 0, stream>>>(xlb, xrb, rowstart, csr, perm, att2, b2, agg, N);
    gnorm_stats_kernel<64><<<G * SPLIT, blk, 0, stream>>>(agg, goff, stats2, SPLIT);
    gnorm_finalize_kernel<64><<<G, 64, 0, stream>>>(stats2, goff, g2w, g2b, g2a, param);

    // Layer 3 (norm of layer 2 fused into GEMM staging)
    gemm2_kernel<128, true><<<(N + 31) / 32, blk, 0, stream>>>(agg, Wl3, Wr3, xlb, xrb, N, param, batch);
    agg128_mean_kernel<<<agg128Grid, blk, 0, stream>>>(xlb, xrb, rowstart, csr, perm, att3, b3, agg, N);
    gnorm_stats_kernel<32><<<G * SPLIT, blk, 0, stream>>>(agg, goff, stats3, SPLIT);
    gnorm_finalize_kernel<32><<<G, 32, 0, stream>>>(stats3, goff, g3w, g3b, g3a, param);
    pool3_kernel<<<G * SPLIT, blk, 0, stream>>>(agg, goff, param, pooled, SPLIT);
    lin_kernel<<<(G * 2 + 63) / 64, 64, 0, stream>>>(pooled, goff, Wlin, blin, outp, G);
}

// Round 5
// 728.960 us; speedup vs baseline: 1.7078x; 1.7078x over previous
//
#include <hip/hip_runtime.h>
#include <hip/hip_bf16.h>

#define LEAKY 0.2f
#define EPS_GN 1e-5f

typedef unsigned int uint;

// ---------------- bf16 helpers (storage only; compute fp32) ----------------

__device__ inline float4 bf4(uint2 u) {
    union { uint u; float f; } a, b, c, d;
    a.u = u.x << 16; b.u = u.x & 0xFFFF0000u;
    c.u = u.y << 16; d.u = u.y & 0xFFFF0000u;
    return make_float4(a.f, b.f, c.f, d.f);
}

__device__ inline uint pack_bf2(float lo, float hi) {
    union { float f; uint u; } x, y; x.f = lo; y.f = hi;
    uint ra = x.u + 0x7FFFu + ((x.u >> 16) & 1u);
    uint rb = y.u + 0x7FFFu + ((y.u >> 16) & 1u);
    return (ra >> 16) | (rb & 0xFFFF0000u);
}

// ---------------- CSR build ----------------

__global__ void zero_int_kernel(int* __restrict__ p, int n) {
    int i = blockIdx.x * blockDim.x + threadIdx.x;
    if (i < n) p[i] = 0;
}

__global__ void hist_kernel(const int* __restrict__ dst, int* __restrict__ deg, int E_, int Etot_) {
    int i = blockIdx.x * blockDim.x + threadIdx.x;
    if (i >= Etot_) return;
    int d = (i < E_) ? dst[i] : (i - E_);
    atomicAdd(&deg[d], 1);
}

__global__ void scan1_kernel(const int* __restrict__ deg, int* __restrict__ bsum, int nN) {
    __shared__ int sd[256];
    int i = blockIdx.x * 256 + threadIdx.x;
    sd[threadIdx.x] = (i < nN) ? deg[i] : 0;
    __syncthreads();
    for (int off = 128; off > 0; off >>= 1) {
        if (threadIdx.x < off) sd[threadIdx.x] += sd[threadIdx.x + off];
        __syncthreads();
    }
    if (threadIdx.x == 0) bsum[blockIdx.x] = sd[0];
}

// also zeroes the csr tail padding (8 ints at csr+Etot)
__global__ void scan2_kernel(const int* __restrict__ bsum, int* __restrict__ bofs, int nb,
                             int* __restrict__ rowstart, int nN, int* __restrict__ csr_pad) {
    if (threadIdx.x == 0 && blockIdx.x == 0) {
        int run = 0;
        for (int i = 0; i < nb; ++i) { bofs[i] = run; run += bsum[i]; }
        rowstart[nN] = run;
        for (int k = 0; k < 8; ++k) csr_pad[k] = 0;
    }
}

__global__ void scan3_kernel(const int* __restrict__ deg, const int* __restrict__ bofs,
                             int* __restrict__ rowstart, int nN) {
    __shared__ int sd[256];
    int i = blockIdx.x * 256 + threadIdx.x;
    int v = (i < nN) ? deg[i] : 0;
    sd[threadIdx.x] = v;
    __syncthreads();
    for (int off = 1; off < 256; off <<= 1) {
        int t = (threadIdx.x >= off) ? sd[threadIdx.x - off] : 0;
        __syncthreads();
        sd[threadIdx.x] += t;
        __syncthreads();
    }
    if (i < nN) rowstart[i] = bofs[blockIdx.x] + sd[threadIdx.x] - v;
}

__global__ void fill_kernel(const int* __restrict__ srcs, const int* __restrict__ dsts,
                            const int* __restrict__ rowstart, int* __restrict__ cursor,
                            int* __restrict__ csr, int E_, int Etot_) {
    int i = blockIdx.x * blockDim.x + threadIdx.x;
    if (i >= Etot_) return;
    int s, d;
    if (i < E_) { s = srcs[i]; d = dsts[i]; } else { s = i - E_; d = s; }
    int pos = rowstart[d] + atomicAdd(&cursor[d], 1);
    csr[pos] = s;
}

__global__ void goff_kernel(const int* __restrict__ batch, int* __restrict__ goff, int nN, int nG) {
    int g = blockIdx.x * blockDim.x + threadIdx.x;
    if (g > nG) return;
    if (g == nG) { goff[g] = nN; return; }
    int lo = 0, hi = nN;
    while (lo < hi) { int mid = (lo + hi) >> 1; if (batch[mid] < g) lo = mid + 1; else hi = mid; }
    goff[g] = lo;
}

// ---------------- GEMM: xl = f(x)@Wl, xr = f(x)@Wr (K=64), bf16 out ----------------

template <int D, bool NORM>
__global__ void gemm2_kernel(const float* __restrict__ x, const float* __restrict__ Wl,
                             const float* __restrict__ Wr, unsigned short* __restrict__ xl,
                             unsigned short* __restrict__ xr, int nN,
                             const float* __restrict__ param, const int* __restrict__ batch) {
    constexpr int TPN = D / 16;
    constexpr int NPB = 256 / TPN;
    __shared__ float w_s[64 * D];
    __shared__ float x_s[NPB][65];
    int tid = threadIdx.x;
    int node0 = blockIdx.x * NPB;
    for (int i = tid; i < NPB * 64; i += 256) {
        int r = i >> 6, c = i & 63;
        int n = node0 + r;
        float v = 0.f;
        if (n < nN) {
            v = x[(size_t)n * 64 + c];
            if constexpr (NORM) {
                int g = batch[n];
                float sc = param[(size_t)g * 128 + c];
                float sh = param[(size_t)g * 128 + 64 + c];
                v = fmaxf(fmaf(sc, v, sh), 0.f);
            }
        }
        x_s[r][c] = v;
    }
    int local = tid / TPN, j0 = (tid % TPN) * 16;
    int n = node0 + local;
    float acc[16];

    for (int i = tid; i < 64 * D; i += 256) w_s[i] = Wl[i];
    __syncthreads();
#pragma unroll
    for (int j = 0; j < 16; ++j) acc[j] = 0.f;
    for (int k = 0; k < 64; ++k) {
        float xv = x_s[local][k];
        const float* wrow = &w_s[k * D + j0];
#pragma unroll
        for (int j = 0; j < 16; ++j) acc[j] = fmaf(xv, wrow[j], acc[j]);
    }
    if (n < nN) {
        uint4* dst = (uint4*)(xl + (size_t)n * D + j0);
        dst[0] = make_uint4(pack_bf2(acc[0], acc[1]), pack_bf2(acc[2], acc[3]),
                            pack_bf2(acc[4], acc[5]), pack_bf2(acc[6], acc[7]));
        dst[1] = make_uint4(pack_bf2(acc[8], acc[9]), pack_bf2(acc[10], acc[11]),
                            pack_bf2(acc[12], acc[13]), pack_bf2(acc[14], acc[15]));
    }
    __syncthreads();

    for (int i = tid; i < 64 * D; i += 256) w_s[i] = Wr[i];
    __syncthreads();
#pragma unroll
    for (int j = 0; j < 16; ++j) acc[j] = 0.f;
    for (int k = 0; k < 64; ++k) {
        float xv = x_s[local][k];
        const float* wrow = &w_s[k * D + j0];
#pragma unroll
        for (int j = 0; j < 16; ++j) acc[j] = fmaf(xv, wrow[j], acc[j]);
    }
    if (n < nN) {
        uint4* dst = (uint4*)(xr + (size_t)n * D + j0);
        dst[0] = make_uint4(pack_bf2(acc[0], acc[1]), pack_bf2(acc[2], acc[3]),
                            pack_bf2(acc[4], acc[5]), pack_bf2(acc[6], acc[7]));
        dst[1] = make_uint4(pack_bf2(acc[8], acc[9]), pack_bf2(acc[10], acc[11]),
                            pack_bf2(acc[12], acc[13]), pack_bf2(acc[14], acc[15]));
    }
}

// ---------------- Aggregate layer 1-2: D=64, H=4, C=16, concat ----------------
// One wave/node, 16 lanes/edge, 4 substreams. No-max softmax, exp2, padded csr.

__global__ void agg64_kernel(const unsigned short* __restrict__ xl, const unsigned short* __restrict__ xr,
                             const int* __restrict__ rowstart, const int* __restrict__ csr,
                             const float* __restrict__ att, const float* __restrict__ bias,
                             float* __restrict__ out, int nN) {
    int wid = (blockIdx.x * blockDim.x + threadIdx.x) >> 6;
    int lane = threadIdx.x & 63;
    if (wid >= nN) return;
    int c4 = lane & 15;
    int sg = lane >> 4;
    const uint2* xl2 = (const uint2*)xl;
    const float LOG2E = 1.4426950408889634f;
    float4 attv = ((const float4*)att)[c4];
    attv.x *= LOG2E; attv.y *= LOG2E; attv.z *= LOG2E; attv.w *= LOG2E;
    float4 xrv = bf4(((const uint2*)xr)[(size_t)wid * 16 + c4]);
    int rs = rowstart[wid], re = rowstart[wid + 1];
    int nIt = (re - rs + 3) >> 2;
    float den = 0.f;
    float4 acc = make_float4(0.f, 0.f, 0.f, 0.f);
    int i = rs + sg;
    int s = csr[i];                       // padded: safe
    uint2 xv = xl2[(size_t)s * 16 + c4];
    for (int it = 0; it < nIt; ++it) {
        float4 cur = bf4(xv);
        bool vv = i < re;
        i += 4;
        s = csr[i];                       // padded: safe, pad=node 0
        xv = xl2[(size_t)s * 16 + c4];    // prefetch next edge
        float4 mm;
        mm.x = cur.x + xrv.x; mm.y = cur.y + xrv.y;
        mm.z = cur.z + xrv.z; mm.w = cur.w + xrv.w;
        mm.x = fmaxf(mm.x, LEAKY * mm.x);
        mm.y = fmaxf(mm.y, LEAKY * mm.y);
        mm.z = fmaxf(mm.z, LEAKY * mm.z);
        mm.w = fmaxf(mm.w, LEAKY * mm.w);
        float p = mm.x * attv.x;
        p = fmaf(mm.y, attv.y, p);
        p = fmaf(mm.z, attv.z, p);
        p = fmaf(mm.w, attv.w, p);
        p += __shfl_xor(p, 1);
        p += __shfl_xor(p, 2);
        float w = vv ? exp2f(p) : 0.f;
        den += w;
        acc.x = fmaf(w, cur.x, acc.x);
        acc.y = fmaf(w, cur.y, acc.y);
        acc.z = fmaf(w, cur.z, acc.z);
        acc.w = fmaf(w, cur.w, acc.w);
    }
    // merge 4 substreams (plain sums)
#pragma unroll
    for (int off = 16; off <= 32; off <<= 1) {
        den   += __shfl_xor(den, off);
        acc.x += __shfl_xor(acc.x, off);
        acc.y += __shfl_xor(acc.y, off);
        acc.z += __shfl_xor(acc.z, off);
        acc.w += __shfl_xor(acc.w, off);
    }
    if (lane < 16) {
        float4 bv = ((const float4*)bias)[c4];
        float inv = 1.f / den;
        float4 r;
        r.x = fmaf(acc.x, inv, bv.x);
        r.y = fmaf(acc.y, inv, bv.y);
        r.z = fmaf(acc.z, inv, bv.z);
        r.w = fmaf(acc.w, inv, bv.w);
        ((float4*)out)[(size_t)wid * 16 + c4] = r;
    }
}

// ---------------- Aggregate layer 3: D=128, H=4, C=32, head-mean ----------------
// One wave/node, 32 lanes/edge, 2 substreams.

__global__ void agg128_mean_kernel(const unsigned short* __restrict__ xl, const unsigned short* __restrict__ xr,
                                   const int* __restrict__ rowstart, const int* __restrict__ csr,
                                   const float* __restrict__ att, const float* __restrict__ bias,
                                   float* __restrict__ out, int nN) {
    int wid = (blockIdx.x * blockDim.x + threadIdx.x) >> 6;
    int lane = threadIdx.x & 63;
    if (wid >= nN) return;
    int c4 = lane & 31;
    int sg = lane >> 5;
    const uint2* xl2 = (const uint2*)xl;
    const float LOG2E = 1.4426950408889634f;
    float4 attv = ((const float4*)att)[c4];
    attv.x *= LOG2E; attv.y *= LOG2E; attv.z *= LOG2E; attv.w *= LOG2E;
    float4 xrv = bf4(((const uint2*)xr)[(size_t)wid * 32 + c4]);
    int rs = rowstart[wid], re = rowstart[wid + 1];
    int nIt = (re - rs + 1) >> 1;
    float den = 0.f;
    float4 acc = make_float4(0.f, 0.f, 0.f, 0.f);
    int i = rs + sg;
    int s = csr[i];
    uint2 xv = xl2[(size_t)s * 32 + c4];
    for (int it = 0; it < nIt; ++it) {
        float4 cur = bf4(xv);
        bool vv = i < re;
        i += 2;
        s = csr[i];                       // padded: safe
        xv = xl2[(size_t)s * 32 + c4];    // prefetch next edge
        float4 mm;
        mm.x = cur.x + xrv.x; mm.y = cur.y + xrv.y;
        mm.z = cur.z + xrv.z; mm.w = cur.w + xrv.w;
        mm.x = fmaxf(mm.x, LEAKY * mm.x);
        mm.y = fmaxf(mm.y, LEAKY * mm.y);
        mm.z = fmaxf(mm.z, LEAKY * mm.z);
        mm.w = fmaxf(mm.w, LEAKY * mm.w);
        float p = mm.x * attv.x;
        p = fmaf(mm.y, attv.y, p);
        p = fmaf(mm.z, attv.z, p);
        p = fmaf(mm.w, attv.w, p);
        p += __shfl_xor(p, 1);
        p += __shfl_xor(p, 2);
        p += __shfl_xor(p, 4);
        float w = vv ? exp2f(p) : 0.f;
        den += w;
        acc.x = fmaf(w, cur.x, acc.x);
        acc.y = fmaf(w, cur.y, acc.y);
        acc.z = fmaf(w, cur.z, acc.z);
        acc.w = fmaf(w, cur.w, acc.w);
    }
    // merge 2 substreams
    den   += __shfl_xor(den, 32);
    acc.x += __shfl_xor(acc.x, 32);
    acc.y += __shfl_xor(acc.y, 32);
    acc.z += __shfl_xor(acc.z, 32);
    acc.w += __shfl_xor(acc.w, 32);
    float inv = 1.f / den;
    float4 r;
    r.x = acc.x * inv; r.y = acc.y * inv; r.z = acc.z * inv; r.w = acc.w * inv;
    // head mean: sum lanes differing in c4 bits 3,4
    r.x += __shfl_xor(r.x, 8);  r.y += __shfl_xor(r.y, 8);
    r.z += __shfl_xor(r.z, 8);  r.w += __shfl_xor(r.w, 8);
    r.x += __shfl_xor(r.x, 16); r.y += __shfl_xor(r.y, 16);
    r.z += __shfl_xor(r.z, 16); r.w += __shfl_xor(r.w, 16);
    if (lane < 8) {
        float4 bv = ((const float4*)bias)[lane];
        float4 o;
        o.x = r.x * 0.25f + bv.x;
        o.y = r.y * 0.25f + bv.y;
        o.z = r.z * 0.25f + bv.z;
        o.w = r.w * 0.25f + bv.w;
        ((float4*)out)[(size_t)wid * 8 + lane] = o;
    }
}

// ---------------- GraphNorm stats / finalize ----------------

template <int D>
__global__ void gnorm_stats_kernel(const float* __restrict__ in, const int* __restrict__ goff,
                                   float* __restrict__ stats, int SPLIT) {
    int g = blockIdx.x / SPLIT, part = blockIdx.x % SPLIT;
    int start = goff[g], end = goff[g + 1];
    constexpr int RPB = 256 / D;
    int tid = threadIdx.x;
    int c = tid % D, sub = tid / D;
    float s1 = 0.f, s2 = 0.f;
    for (int n = start + part * RPB + sub; n < end; n += SPLIT * RPB) {
        float v = in[(size_t)n * D + c];
        s1 += v; s2 += v * v;
    }
    __shared__ float l1[256], l2[256];
    l1[tid] = s1; l2[tid] = s2;
    __syncthreads();
    if (tid < D) {
        for (int s = 1; s < RPB; ++s) { s1 += l1[s * D + tid]; s2 += l2[s * D + tid]; }
        atomicAdd(&stats[(size_t)g * 2 * D + tid], s1);
        atomicAdd(&stats[(size_t)g * 2 * D + D + tid], s2);
    }
}

template <int D>
__global__ void gnorm_finalize_kernel(const float* __restrict__ stats, const int* __restrict__ goff,
                                      const float* __restrict__ w, const float* __restrict__ b,
                                      const float* __restrict__ a, float* __restrict__ param) {
    int g = blockIdx.x, c = threadIdx.x;
    if (c >= D) return;
    int cn = goff[g + 1] - goff[g];
    float cnt = (float)(cn > 1 ? cn : 1);
    float S1 = stats[(size_t)g * 2 * D + c], S2 = stats[(size_t)g * 2 * D + D + c];
    float mu = S1 / cnt;
    float am = a[c] * mu;
    float var = S2 / cnt - 2.f * am * mu + am * am;
    float sc = w[c] * rsqrtf(var + EPS_GN);
    param[(size_t)g * 2 * D + c] = sc;
    param[(size_t)g * 2 * D + D + c] = b[c] - sc * am;
}

// ---------------- layer-3 tail ----------------

__global__ void pool3_kernel(const float* __restrict__ in, const int* __restrict__ goff,
                             const float* __restrict__ param, float* __restrict__ pooled, int SPLIT) {
    int g = blockIdx.x / SPLIT, part = blockIdx.x % SPLIT;
    int start = goff[g], end = goff[g + 1];
    int tid = threadIdx.x;
    int c = tid & 31, sub = tid >> 5;
    float sc = param[(size_t)g * 64 + c], sh = param[(size_t)g * 64 + 32 + c];
    float s = 0.f;
    for (int n = start + part * 8 + sub; n < end; n += SPLIT * 8)
        s += fmaxf(fmaf(sc, in[(size_t)n * 32 + c], sh), 0.f);
    __shared__ float l[256];
    l[tid] = s;
    __syncthreads();
    if (tid < 32) {
        for (int q = 1; q < 8; ++q) s += l[q * 32 + tid];
        atomicAdd(&pooled[(size_t)g * 32 + tid], s);
    }
}

__global__ void lin_kernel(const float* __restrict__ pooled, const int* __restrict__ goff,
                           const float* __restrict__ Wlin, const float* __restrict__ blin,
                           float* __restrict__ out, int nG) {
    int idx = blockIdx.x * blockDim.x + threadIdx.x;
    if (idx >= nG * 2) return;
    int g = idx >> 1, o = idx & 1;
    int cn = goff[g + 1] - goff[g];
    float inv = 1.f / (float)(cn > 1 ? cn : 1);
    float acc = blin[o];
    for (int c = 0; c < 32; ++c) acc = fmaf(pooled[(size_t)g * 32 + c] * inv, Wlin[c * 2 + o], acc);
    out[idx] = acc;
}

// ---------------- launch ----------------

extern "C" void kernel_launch(void* const* d_in, const int* in_sizes, int n_in,
                              void* d_out, int out_size, void* d_ws, size_t ws_size,
                              hipStream_t stream) {
    const float* x    = (const float*)d_in[0];
    const int*  eidx  = (const int*)d_in[1];
    const int*  batch = (const int*)d_in[2];
    const float* Wl1 = (const float*)d_in[3];
    const float* Wr1 = (const float*)d_in[4];
    const float* att1 = (const float*)d_in[5];
    const float* b1 = (const float*)d_in[6];
    const float* g1w = (const float*)d_in[7];
    const float* g1b = (const float*)d_in[8];
    const float* g1a = (const float*)d_in[9];
    const float* Wl2 = (const float*)d_in[10];
    const float* Wr2 = (const float*)d_in[11];
    const float* att2 = (const float*)d_in[12];
    const float* b2 = (const float*)d_in[13];
    const float* g2w = (const float*)d_in[14];
    const float* g2b = (const float*)d_in[15];
    const float* g2a = (const float*)d_in[16];
    const float* Wl3 = (const float*)d_in[17];
    const float* Wr3 = (const float*)d_in[18];
    const float* att3 = (const float*)d_in[19];
    const float* b3 = (const float*)d_in[20];
    const float* g3w = (const float*)d_in[21];
    const float* g3b = (const float*)d_in[22];
    const float* g3a = (const float*)d_in[23];
    const float* Wlin = (const float*)d_in[24];
    const float* blin = (const float*)d_in[25];
    float* outp = (float*)d_out;

    const int N = in_sizes[0] / 64;
    const int E = in_sizes[1] / 2;
    const int Etot = N + E;
    const int G = out_size / 2;
    const int NB = (N + 255) / 256;
    const int SPLIT = 16;

    unsigned short* xlb = (unsigned short*)d_ws;           // N*128 bf16
    unsigned short* xrb = xlb + (size_t)N * 128;           // N*128 bf16
    float* agg   = (float*)(xrb + (size_t)N * 128);        // N*64 f32
    float* stats = agg + (size_t)N * 64;
    float* stats1 = stats;
    float* stats2 = stats1 + (size_t)G * 128;
    float* stats3 = stats2 + (size_t)G * 128;
    float* pooled = stats3 + (size_t)G * 64;
    float* param  = pooled + (size_t)G * 32;               // G*128, reused per layer
    int* deg      = (int*)(param + (size_t)G * 128);
    int* cursor   = deg + N;
    int* rowstart = cursor + N;
    int* csr      = rowstart + (N + 1);
    int* bsum     = csr + Etot + 8;                        // +8 pad for clamp-free loop
    int* bofs     = bsum + NB;
    int* goff     = bofs + NB;

    const int* src_idx = eidx;
    const int* dst_idx = eidx + E;

    zero_int_kernel<<<(2 * N + 255) / 256, 256, 0, stream>>>(deg, 2 * N);
    zero_int_kernel<<<(G * 352 + 255) / 256, 256, 0, stream>>>((int*)stats, G * 352);

    hist_kernel<<<(Etot + 255) / 256, 256, 0, stream>>>(dst_idx, deg, E, Etot);
    scan1_kernel<<<NB, 256, 0, stream>>>(deg, bsum, N);
    scan2_kernel<<<1, 64, 0, stream>>>(bsum, bofs, NB, rowstart, N, csr + Etot);
    scan3_kernel<<<NB, 256, 0, stream>>>(deg, bofs, rowstart, N);
    fill_kernel<<<(Etot + 255) / 256, 256, 0, stream>>>(src_idx, dst_idx, rowstart, cursor, csr, E, Etot);
    goff_kernel<<<1, 128, 0, stream>>>(batch, goff, N, G);

    dim3 blk(256);
    int aggGrid = (N + 3) / 4;

    // Layer 1
    gemm2_kernel<64, false><<<(N + 63) / 64, blk, 0, stream>>>(x, Wl1, Wr1, xlb, xrb, N, nullptr, nullptr);
    agg64_kernel<<<aggGrid, blk, 0, stream>>>(xlb, xrb, rowstart, csr, att1, b1, agg, N);
    gnorm_stats_kernel<64><<<G * SPLIT, blk, 0, stream>>>(agg, goff, stats1, SPLIT);
    gnorm_finalize_kernel<64><<<G, 64, 0, stream>>>(stats1, goff, g1w, g1b, g1a, param);

    // Layer 2 (norm of layer 1 fused into GEMM staging)
    gemm2_kernel<64, true><<<(N + 63) / 64, blk, 0, stream>>>(agg, Wl2, Wr2, xlb, xrb, N, param, batch);
    agg64_kernel<<<aggGrid, blk, 0, stream>>>(xlb, xrb, rowstart, csr, att2, b2, agg, N);
    gnorm_stats_kernel<64><<<G * SPLIT, blk, 0, stream>>>(agg, goff, stats2, SPLIT);
    gnorm_finalize_kernel<64><<<G, 64, 0, stream>>>(stats2, goff, g2w, g2b, g2a, param);

    // Layer 3 (norm of layer 2 fused into GEMM staging)
    gemm2_kernel<128, true><<<(N + 31) / 32, blk, 0, stream>>>(agg, Wl3, Wr3, xlb, xrb, N, param, batch);
    agg128_mean_kernel<<<aggGrid, blk, 0, stream>>>(xlb, xrb, rowstart, csr, att3, b3, agg, N);
    gnorm_stats_kernel<32><<<G * SPLIT, blk, 0, stream>>>(agg, goff, stats3, SPLIT);
    gnorm_finalize_kernel<32><<<G, 32, 0, stream>>>(stats3, goff, g3w, g3b, g3a, param);
    pool3_kernel<<<G * SPLIT, blk, 0, stream>>>(agg, goff, param, pooled, SPLIT);
    lin_kernel<<<(G * 2 + 63) / 64, 64, 0, stream>>>(pooled, goff, Wlin, blin, outp, G);
}

// Round 6
// 646.119 us; speedup vs baseline: 1.9268x; 1.1282x over previous
//
#include <hip/hip_runtime.h>
#include <hip/hip_bf16.h>

#define LEAKY 0.2f
#define EPS_GN 1e-5f

typedef unsigned int uint;

// ---------------- bf16 helpers (storage only; compute fp32) ----------------

__device__ inline float4 bf4(uint lo, uint hi) {
    union { uint u; float f; } a, b, c, d;
    a.u = lo << 16; b.u = lo & 0xFFFF0000u;
    c.u = hi << 16; d.u = hi & 0xFFFF0000u;
    return make_float4(a.f, b.f, c.f, d.f);
}

__device__ inline uint pack_bf2(float lo, float hi) {
    union { float f; uint u; } x, y; x.f = lo; y.f = hi;
    uint ra = x.u + 0x7FFFu + ((x.u >> 16) & 1u);
    uint rb = y.u + 0x7FFFu + ((y.u >> 16) & 1u);
    return (ra >> 16) | (rb & 0xFFFF0000u);
}

// ---------------- CSR build ----------------

__global__ void zero_int_kernel(int* __restrict__ p, int n) {
    int i = blockIdx.x * blockDim.x + threadIdx.x;
    if (i < n) p[i] = 0;
}

__global__ void hist_kernel(const int* __restrict__ dst, int* __restrict__ deg, int E_, int Etot_) {
    int i = blockIdx.x * blockDim.x + threadIdx.x;
    if (i >= Etot_) return;
    int d = (i < E_) ? dst[i] : (i - E_);
    atomicAdd(&deg[d], 1);
}

__global__ void scan1_kernel(const int* __restrict__ deg, int* __restrict__ bsum, int nN) {
    __shared__ int sd[256];
    int i = blockIdx.x * 256 + threadIdx.x;
    sd[threadIdx.x] = (i < nN) ? deg[i] : 0;
    __syncthreads();
    for (int off = 128; off > 0; off >>= 1) {
        if (threadIdx.x < off) sd[threadIdx.x] += sd[threadIdx.x + off];
        __syncthreads();
    }
    if (threadIdx.x == 0) bsum[blockIdx.x] = sd[0];
}

// parallel scan over up to 512 block sums; also zeroes csr pad (16 ints)
__global__ void scan2_kernel(const int* __restrict__ bsum, int* __restrict__ bofs, int nb,
                             int* __restrict__ rowstart, int nN, int* __restrict__ csr_pad) {
    __shared__ int sd[512];
    int tid = threadIdx.x;
    int v = (tid < nb) ? bsum[tid] : 0;
    sd[tid] = v;
    __syncthreads();
    for (int off = 1; off < 512; off <<= 1) {
        int t = (tid >= off) ? sd[tid - off] : 0;
        __syncthreads();
        sd[tid] += t;
        __syncthreads();
    }
    if (tid < nb) bofs[tid] = sd[tid] - v;
    if (tid == 511) rowstart[nN] = sd[511];
    if (tid < 16) csr_pad[tid] = 0;
}

__global__ void scan3_kernel(const int* __restrict__ deg, const int* __restrict__ bofs,
                             int* __restrict__ rowstart, int nN) {
    __shared__ int sd[256];
    int i = blockIdx.x * 256 + threadIdx.x;
    int v = (i < nN) ? deg[i] : 0;
    sd[threadIdx.x] = v;
    __syncthreads();
    for (int off = 1; off < 256; off <<= 1) {
        int t = (threadIdx.x >= off) ? sd[threadIdx.x - off] : 0;
        __syncthreads();
        sd[threadIdx.x] += t;
        __syncthreads();
    }
    if (i < nN) rowstart[i] = bofs[blockIdx.x] + sd[threadIdx.x] - v;
}

__global__ void fill_kernel(const int* __restrict__ srcs, const int* __restrict__ dsts,
                            const int* __restrict__ rowstart, int* __restrict__ cursor,
                            int* __restrict__ csr, int E_, int Etot_) {
    int i = blockIdx.x * blockDim.x + threadIdx.x;
    if (i >= Etot_) return;
    int s, d;
    if (i < E_) { s = srcs[i]; d = dsts[i]; } else { s = i - E_; d = s; }
    int pos = rowstart[d] + atomicAdd(&cursor[d], 1);
    csr[pos] = s;
}

__global__ void goff_kernel(const int* __restrict__ batch, int* __restrict__ goff, int nN, int nG) {
    int g = blockIdx.x * blockDim.x + threadIdx.x;
    if (g > nG) return;
    if (g == nG) { goff[g] = nN; return; }
    int lo = 0, hi = nN;
    while (lo < hi) { int mid = (lo + hi) >> 1; if (batch[mid] < g) lo = mid + 1; else hi = mid; }
    goff[g] = lo;
}

// ---------------- GEMM: xl = f(x)@Wl, xr = f(x)@Wr (K=64), bf16 out ----------------

template <int D, bool NORM>
__global__ void gemm2_kernel(const float* __restrict__ x, const float* __restrict__ Wl,
                             const float* __restrict__ Wr, unsigned short* __restrict__ xl,
                             unsigned short* __restrict__ xr, int nN,
                             const float* __restrict__ param, const int* __restrict__ batch) {
    constexpr int TPN = D / 16;
    constexpr int NPB = 256 / TPN;
    __shared__ float w_s[64 * D];
    __shared__ float x_s[NPB][65];
    int tid = threadIdx.x;
    int node0 = blockIdx.x * NPB;
    for (int i = tid; i < NPB * 64; i += 256) {
        int r = i >> 6, c = i & 63;
        int n = node0 + r;
        float v = 0.f;
        if (n < nN) {
            v = x[(size_t)n * 64 + c];
            if constexpr (NORM) {
                int g = batch[n];
                float sc = param[(size_t)g * 128 + c];
                float sh = param[(size_t)g * 128 + 64 + c];
                v = fmaxf(fmaf(sc, v, sh), 0.f);
            }
        }
        x_s[r][c] = v;
    }
    int local = tid / TPN, j0 = (tid % TPN) * 16;
    int n = node0 + local;
    float acc[16];

    for (int i = tid; i < 64 * D; i += 256) w_s[i] = Wl[i];
    __syncthreads();
#pragma unroll
    for (int j = 0; j < 16; ++j) acc[j] = 0.f;
    for (int k = 0; k < 64; ++k) {
        float xv = x_s[local][k];
        const float* wrow = &w_s[k * D + j0];
#pragma unroll
        for (int j = 0; j < 16; ++j) acc[j] = fmaf(xv, wrow[j], acc[j]);
    }
    if (n < nN) {
        uint4* dst = (uint4*)(xl + (size_t)n * D + j0);
        dst[0] = make_uint4(pack_bf2(acc[0], acc[1]), pack_bf2(acc[2], acc[3]),
                            pack_bf2(acc[4], acc[5]), pack_bf2(acc[6], acc[7]));
        dst[1] = make_uint4(pack_bf2(acc[8], acc[9]), pack_bf2(acc[10], acc[11]),
                            pack_bf2(acc[12], acc[13]), pack_bf2(acc[14], acc[15]));
    }
    __syncthreads();

    for (int i = tid; i < 64 * D; i += 256) w_s[i] = Wr[i];
    __syncthreads();
#pragma unroll
    for (int j = 0; j < 16; ++j) acc[j] = 0.f;
    for (int k = 0; k < 64; ++k) {
        float xv = x_s[local][k];
        const float* wrow = &w_s[k * D + j0];
#pragma unroll
        for (int j = 0; j < 16; ++j) acc[j] = fmaf(xv, wrow[j], acc[j]);
    }
    if (n < nN) {
        uint4* dst = (uint4*)(xr + (size_t)n * D + j0);
        dst[0] = make_uint4(pack_bf2(acc[0], acc[1]), pack_bf2(acc[2], acc[3]),
                            pack_bf2(acc[4], acc[5]), pack_bf2(acc[6], acc[7]));
        dst[1] = make_uint4(pack_bf2(acc[8], acc[9]), pack_bf2(acc[10], acc[11]),
                            pack_bf2(acc[12], acc[13]), pack_bf2(acc[14], acc[15]));
    }
}

// ---------------- Aggregate layer 1-2: D=64, H=4, C=16, concat ----------------
// One wave/node, 8 lanes/edge (uint4 = 8ch/lane), 8 substreams. No-max exp2 softmax.

__global__ void agg64_kernel(const unsigned short* __restrict__ xl, const unsigned short* __restrict__ xr,
                             const int* __restrict__ rowstart, const int* __restrict__ csr,
                             const float* __restrict__ att, const float* __restrict__ bias,
                             float* __restrict__ out, int nN) {
    int wid = (blockIdx.x * blockDim.x + threadIdx.x) >> 6;
    int lane = threadIdx.x & 63;
    if (wid >= nN) return;
    int c8 = lane & 7;            // channels c8*8 .. c8*8+7; head = c8>>1
    int sg = lane >> 3;           // 8 edge substreams
    const uint4* xl4 = (const uint4*)xl;  // row stride 8 uint4
    const float LOG2E = 1.4426950408889634f;
    float4 attA = ((const float4*)att)[c8 * 2];
    float4 attB = ((const float4*)att)[c8 * 2 + 1];
    attA.x *= LOG2E; attA.y *= LOG2E; attA.z *= LOG2E; attA.w *= LOG2E;
    attB.x *= LOG2E; attB.y *= LOG2E; attB.z *= LOG2E; attB.w *= LOG2E;
    uint4 xru = ((const uint4*)xr)[(size_t)wid * 8 + c8];
    float4 xrA = bf4(xru.x, xru.y), xrB = bf4(xru.z, xru.w);
    int rs = rowstart[wid], re = rowstart[wid + 1];
    int nIt = (re - rs + 7) >> 3;
    float den = 0.f;
    float4 accA = make_float4(0.f, 0.f, 0.f, 0.f);
    float4 accB = make_float4(0.f, 0.f, 0.f, 0.f);
    int i = rs + sg;
    int s = csr[i];                        // padded (16): safe
    uint4 xv = xl4[(size_t)s * 8 + c8];
    for (int it = 0; it < nIt; ++it) {
        float4 curA = bf4(xv.x, xv.y), curB = bf4(xv.z, xv.w);
        bool vv = i < re;
        i += 8;
        s = csr[i];                        // padded: safe, pad=node 0
        xv = xl4[(size_t)s * 8 + c8];      // prefetch next edge
        float4 mA, mB;
        mA.x = curA.x + xrA.x; mA.y = curA.y + xrA.y;
        mA.z = curA.z + xrA.z; mA.w = curA.w + xrA.w;
        mB.x = curB.x + xrB.x; mB.y = curB.y + xrB.y;
        mB.z = curB.z + xrB.z; mB.w = curB.w + xrB.w;
        mA.x = fmaxf(mA.x, LEAKY * mA.x); mA.y = fmaxf(mA.y, LEAKY * mA.y);
        mA.z = fmaxf(mA.z, LEAKY * mA.z); mA.w = fmaxf(mA.w, LEAKY * mA.w);
        mB.x = fmaxf(mB.x, LEAKY * mB.x); mB.y = fmaxf(mB.y, LEAKY * mB.y);
        mB.z = fmaxf(mB.z, LEAKY * mB.z); mB.w = fmaxf(mB.w, LEAKY * mB.w);
        float p = mA.x * attA.x;
        p = fmaf(mA.y, attA.y, p); p = fmaf(mA.z, attA.z, p); p = fmaf(mA.w, attA.w, p);
        p = fmaf(mB.x, attB.x, p); p = fmaf(mB.y, attB.y, p);
        p = fmaf(mB.z, attB.z, p); p = fmaf(mB.w, attB.w, p);
        p += __shfl_xor(p, 1);             // sum over the head's 2 lanes (16 ch)
        float w = vv ? exp2f(p) : 0.f;
        den += w;
        accA.x = fmaf(w, curA.x, accA.x); accA.y = fmaf(w, curA.y, accA.y);
        accA.z = fmaf(w, curA.z, accA.z); accA.w = fmaf(w, curA.w, accA.w);
        accB.x = fmaf(w, curB.x, accB.x); accB.y = fmaf(w, curB.y, accB.y);
        accB.z = fmaf(w, curB.z, accB.z); accB.w = fmaf(w, curB.w, accB.w);
    }
    // merge 8 substreams (plain sums)
#pragma unroll
    for (int off = 8; off <= 32; off <<= 1) {
        den    += __shfl_xor(den, off);
        accA.x += __shfl_xor(accA.x, off); accA.y += __shfl_xor(accA.y, off);
        accA.z += __shfl_xor(accA.z, off); accA.w += __shfl_xor(accA.w, off);
        accB.x += __shfl_xor(accB.x, off); accB.y += __shfl_xor(accB.y, off);
        accB.z += __shfl_xor(accB.z, off); accB.w += __shfl_xor(accB.w, off);
    }
    if (lane < 8) {
        float4 bvA = ((const float4*)bias)[c8 * 2];
        float4 bvB = ((const float4*)bias)[c8 * 2 + 1];
        float inv = 1.f / den;
        float4 rA, rB;
        rA.x = fmaf(accA.x, inv, bvA.x); rA.y = fmaf(accA.y, inv, bvA.y);
        rA.z = fmaf(accA.z, inv, bvA.z); rA.w = fmaf(accA.w, inv, bvA.w);
        rB.x = fmaf(accB.x, inv, bvB.x); rB.y = fmaf(accB.y, inv, bvB.y);
        rB.z = fmaf(accB.z, inv, bvB.z); rB.w = fmaf(accB.w, inv, bvB.w);
        ((float4*)out)[(size_t)wid * 16 + c8 * 2]     = rA;
        ((float4*)out)[(size_t)wid * 16 + c8 * 2 + 1] = rB;
    }
}

// ---------------- Aggregate layer 3: D=128, H=4, C=32, head-mean ----------------
// One wave/node, 16 lanes/edge (uint4 = 8ch/lane), 4 substreams.

__global__ void agg128_mean_kernel(const unsigned short* __restrict__ xl, const unsigned short* __restrict__ xr,
                                   const int* __restrict__ rowstart, const int* __restrict__ csr,
                                   const float* __restrict__ att, const float* __restrict__ bias,
                                   float* __restrict__ out, int nN) {
    int wid = (blockIdx.x * blockDim.x + threadIdx.x) >> 6;
    int lane = threadIdx.x & 63;
    if (wid >= nN) return;
    int c8 = lane & 15;           // channels c8*8 .. c8*8+7; head = c8>>2
    int sg = lane >> 4;           // 4 edge substreams
    const uint4* xl4 = (const uint4*)xl;  // row stride 16 uint4
    const float LOG2E = 1.4426950408889634f;
    float4 attA = ((const float4*)att)[c8 * 2];
    float4 attB = ((const float4*)att)[c8 * 2 + 1];
    attA.x *= LOG2E; attA.y *= LOG2E; attA.z *= LOG2E; attA.w *= LOG2E;
    attB.x *= LOG2E; attB.y *= LOG2E; attB.z *= LOG2E; attB.w *= LOG2E;
    uint4 xru = ((const uint4*)xr)[(size_t)wid * 16 + c8];
    float4 xrA = bf4(xru.x, xru.y), xrB = bf4(xru.z, xru.w);
    int rs = rowstart[wid], re = rowstart[wid + 1];
    int nIt = (re - rs + 3) >> 2;
    float den = 0.f;
    float4 accA = make_float4(0.f, 0.f, 0.f, 0.f);
    float4 accB = make_float4(0.f, 0.f, 0.f, 0.f);
    int i = rs + sg;
    int s = csr[i];                        // padded: safe
    uint4 xv = xl4[(size_t)s * 16 + c8];
    for (int it = 0; it < nIt; ++it) {
        float4 curA = bf4(xv.x, xv.y), curB = bf4(xv.z, xv.w);
        bool vv = i < re;
        i += 4;
        s = csr[i];                        // padded: safe
        xv = xl4[(size_t)s * 16 + c8];     // prefetch next edge
        float4 mA, mB;
        mA.x = curA.x + xrA.x; mA.y = curA.y + xrA.y;
        mA.z = curA.z + xrA.z; mA.w = curA.w + xrA.w;
        mB.x = curB.x + xrB.x; mB.y = curB.y + xrB.y;
        mB.z = curB.z + xrB.z; mB.w = curB.w + xrB.w;
        mA.x = fmaxf(mA.x, LEAKY * mA.x); mA.y = fmaxf(mA.y, LEAKY * mA.y);
        mA.z = fmaxf(mA.z, LEAKY * mA.z); mA.w = fmaxf(mA.w, LEAKY * mA.w);
        mB.x = fmaxf(mB.x, LEAKY * mB.x); mB.y = fmaxf(mB.y, LEAKY * mB.y);
        mB.z = fmaxf(mB.z, LEAKY * mB.z); mB.w = fmaxf(mB.w, LEAKY * mB.w);
        float p = mA.x * attA.x;
        p = fmaf(mA.y, attA.y, p); p = fmaf(mA.z, attA.z, p); p = fmaf(mA.w, attA.w, p);
        p = fmaf(mB.x, attB.x, p); p = fmaf(mB.y, attB.y, p);
        p = fmaf(mB.z, attB.z, p); p = fmaf(mB.w, attB.w, p);
        p += __shfl_xor(p, 1);
        p += __shfl_xor(p, 2);             // sum over the head's 4 lanes (32 ch)
        float w = vv ? exp2f(p) : 0.f;
        den += w;
        accA.x = fmaf(w, curA.x, accA.x); accA.y = fmaf(w, curA.y, accA.y);
        accA.z = fmaf(w, curA.z, accA.z); accA.w = fmaf(w, curA.w, accA.w);
        accB.x = fmaf(w, curB.x, accB.x); accB.y = fmaf(w, curB.y, accB.y);
        accB.z = fmaf(w, curB.z, accB.z); accB.w = fmaf(w, curB.w, accB.w);
    }
    // merge 4 substreams
#pragma unroll
    for (int off = 16; off <= 32; off <<= 1) {
        den    += __shfl_xor(den, off);
        accA.x += __shfl_xor(accA.x, off); accA.y += __shfl_xor(accA.y, off);
        accA.z += __shfl_xor(accA.z, off); accA.w += __shfl_xor(accA.w, off);
        accB.x += __shfl_xor(accB.x, off); accB.y += __shfl_xor(accB.y, off);
        accB.z += __shfl_xor(accB.z, off); accB.w += __shfl_xor(accB.w, off);
    }
    float inv = 1.f / den;
    float4 rA, rB;
    rA.x = accA.x * inv; rA.y = accA.y * inv; rA.z = accA.z * inv; rA.w = accA.w * inv;
    rB.x = accB.x * inv; rB.y = accB.y * inv; rB.z = accB.z * inv; rB.w = accB.w * inv;
    // head mean: sum over lanes differing in c8 bits 2,3 (the 4 heads)
#pragma unroll
    for (int off = 4; off <= 8; off <<= 1) {
        rA.x += __shfl_xor(rA.x, off); rA.y += __shfl_xor(rA.y, off);
        rA.z += __shfl_xor(rA.z, off); rA.w += __shfl_xor(rA.w, off);
        rB.x += __shfl_xor(rB.x, off); rB.y += __shfl_xor(rB.y, off);
        rB.z += __shfl_xor(rB.z, off); rB.w += __shfl_xor(rB.w, off);
    }
    if (lane < 4) {
        float4 bvA = ((const float4*)bias)[lane * 2];
        float4 bvB = ((const float4*)bias)[lane * 2 + 1];
        float4 oA, oB;
        oA.x = fmaf(rA.x, 0.25f, bvA.x); oA.y = fmaf(rA.y, 0.25f, bvA.y);
        oA.z = fmaf(rA.z, 0.25f, bvA.z); oA.w = fmaf(rA.w, 0.25f, bvA.w);
        oB.x = fmaf(rB.x, 0.25f, bvB.x); oB.y = fmaf(rB.y, 0.25f, bvB.y);
        oB.z = fmaf(rB.z, 0.25f, bvB.z); oB.w = fmaf(rB.w, 0.25f, bvB.w);
        ((float4*)out)[(size_t)wid * 8 + lane * 2]     = oA;
        ((float4*)out)[(size_t)wid * 8 + lane * 2 + 1] = oB;
    }
}

// ---------------- GraphNorm stats / finalize ----------------

template <int D>
__global__ void gnorm_stats_kernel(const float* __restrict__ in, const int* __restrict__ goff,
                                   float* __restrict__ stats, int SPLIT) {
    int g = blockIdx.x / SPLIT, part = blockIdx.x % SPLIT;
    int start = goff[g], end = goff[g + 1];
    constexpr int RPB = 256 / D;
    int tid = threadIdx.x;
    int c = tid % D, sub = tid / D;
    float s1 = 0.f, s2 = 0.f;
    for (int n = start + part * RPB + sub; n < end; n += SPLIT * RPB) {
        float v = in[(size_t)n * D + c];
        s1 += v; s2 += v * v;
    }
    __shared__ float l1[256], l2[256];
    l1[tid] = s1; l2[tid] = s2;
    __syncthreads();
    if (tid < D) {
        for (int s = 1; s < RPB; ++s) { s1 += l1[s * D + tid]; s2 += l2[s * D + tid]; }
        atomicAdd(&stats[(size_t)g * 2 * D + tid], s1);
        atomicAdd(&stats[(size_t)g * 2 * D + D + tid], s2);
    }
}

template <int D>
__global__ void gnorm_finalize_kernel(const float* __restrict__ stats, const int* __restrict__ goff,
                                      const float* __restrict__ w, const float* __restrict__ b,
                                      const float* __restrict__ a, float* __restrict__ param) {
    int g = blockIdx.x, c = threadIdx.x;
    if (c >= D) return;
    int cn = goff[g + 1] - goff[g];
    float cnt = (float)(cn > 1 ? cn : 1);
    float S1 = stats[(size_t)g * 2 * D + c], S2 = stats[(size_t)g * 2 * D + D + c];
    float mu = S1 / cnt;
    float am = a[c] * mu;
    float var = S2 / cnt - 2.f * am * mu + am * am;
    float sc = w[c] * rsqrtf(var + EPS_GN);
    param[(size_t)g * 2 * D + c] = sc;
    param[(size_t)g * 2 * D + D + c] = b[c] - sc * am;
}

// ---------------- layer-3 tail ----------------

__global__ void pool3_kernel(const float* __restrict__ in, const int* __restrict__ goff,
                             const float* __restrict__ param, float* __restrict__ pooled, int SPLIT) {
    int g = blockIdx.x / SPLIT, part = blockIdx.x % SPLIT;
    int start = goff[g], end = goff[g + 1];
    int tid = threadIdx.x;
    int c = tid & 31, sub = tid >> 5;
    float sc = param[(size_t)g * 64 + c], sh = param[(size_t)g * 64 + 32 + c];
    float s = 0.f;
    for (int n = start + part * 8 + sub; n < end; n += SPLIT * 8)
        s += fmaxf(fmaf(sc, in[(size_t)n * 32 + c], sh), 0.f);
    __shared__ float l[256];
    l[tid] = s;
    __syncthreads();
    if (tid < 32) {
        for (int q = 1; q < 8; ++q) s += l[q * 32 + tid];
        atomicAdd(&pooled[(size_t)g * 32 + tid], s);
    }
}

__global__ void lin_kernel(const float* __restrict__ pooled, const int* __restrict__ goff,
                           const float* __restrict__ Wlin, const float* __restrict__ blin,
                           float* __restrict__ out, int nG) {
    int idx = blockIdx.x * blockDim.x + threadIdx.x;
    if (idx >= nG * 2) return;
    int g = idx >> 1, o = idx & 1;
    int cn = goff[g + 1] - goff[g];
    float inv = 1.f / (float)(cn > 1 ? cn : 1);
    float acc = blin[o];
    for (int c = 0; c < 32; ++c) acc = fmaf(pooled[(size_t)g * 32 + c] * inv, Wlin[c * 2 + o], acc);
    out[idx] = acc;
}

// ---------------- launch ----------------

extern "C" void kernel_launch(void* const* d_in, const int* in_sizes, int n_in,
                              void* d_out, int out_size, void* d_ws, size_t ws_size,
                              hipStream_t stream) {
    const float* x    = (const float*)d_in[0];
    const int*  eidx  = (const int*)d_in[1];
    const int*  batch = (const int*)d_in[2];
    const float* Wl1 = (const float*)d_in[3];
    const float* Wr1 = (const float*)d_in[4];
    const float* att1 = (const float*)d_in[5];
    const float* b1 = (const float*)d_in[6];
    const float* g1w = (const float*)d_in[7];
    const float* g1b = (const float*)d_in[8];
    const float* g1a = (const float*)d_in[9];
    const float* Wl2 = (const float*)d_in[10];
    const float* Wr2 = (const float*)d_in[11];
    const float* att2 = (const float*)d_in[12];
    const float* b2 = (const float*)d_in[13];
    const float* g2w = (const float*)d_in[14];
    const float* g2b = (const float*)d_in[15];
    const float* g2a = (const float*)d_in[16];
    const float* Wl3 = (const float*)d_in[17];
    const float* Wr3 = (const float*)d_in[18];
    const float* att3 = (const float*)d_in[19];
    const float* b3 = (const float*)d_in[20];
    const float* g3w = (const float*)d_in[21];
    const float* g3b = (const float*)d_in[22];
    const float* g3a = (const float*)d_in[23];
    const float* Wlin = (const float*)d_in[24];
    const float* blin = (const float*)d_in[25];
    float* outp = (float*)d_out;

    const int N = in_sizes[0] / 64;
    const int E = in_sizes[1] / 2;
    const int Etot = N + E;
    const int G = out_size / 2;
    const int NB = (N + 255) / 256;
    const int SPLIT = 16;

    unsigned short* xlb = (unsigned short*)d_ws;           // N*128 bf16
    unsigned short* xrb = xlb + (size_t)N * 128;           // N*128 bf16
    float* agg   = (float*)(xrb + (size_t)N * 128);        // N*64 f32
    float* stats = agg + (size_t)N * 64;
    float* stats1 = stats;
    float* stats2 = stats1 + (size_t)G * 128;
    float* stats3 = stats2 + (size_t)G * 128;
    float* pooled = stats3 + (size_t)G * 64;
    float* param  = pooled + (size_t)G * 32;               // G*128, reused per layer
    int* deg      = (int*)(param + (size_t)G * 128);
    int* cursor   = deg + N;
    int* rowstart = cursor + N;
    int* csr      = rowstart + (N + 1);
    int* bsum     = csr + Etot + 16;                       // +16 pad for clamp-free loop
    int* bofs     = bsum + NB;
    int* goff     = bofs + NB;

    const int* src_idx = eidx;
    const int* dst_idx = eidx + E;

    zero_int_kernel<<<(2 * N + 255) / 256, 256, 0, stream>>>(deg, 2 * N);
    zero_int_kernel<<<(G * 352 + 255) / 256, 256, 0, stream>>>((int*)stats, G * 352);

    hist_kernel<<<(Etot + 255) / 256, 256, 0, stream>>>(dst_idx, deg, E, Etot);
    scan1_kernel<<<NB, 256, 0, stream>>>(deg, bsum, N);
    scan2_kernel<<<1, 512, 0, stream>>>(bsum, bofs, NB, rowstart, N, csr + Etot);
    scan3_kernel<<<NB, 256, 0, stream>>>(deg, bofs, rowstart, N);
    fill_kernel<<<(Etot + 255) / 256, 256, 0, stream>>>(src_idx, dst_idx, rowstart, cursor, csr, E, Etot);
    goff_kernel<<<1, 128, 0, stream>>>(batch, goff, N, G);

    dim3 blk(256);
    int aggGrid = (N + 3) / 4;

    // Layer 1
    gemm2_kernel<64, false><<<(N + 63) / 64, blk, 0, stream>>>(x, Wl1, Wr1, xlb, xrb, N, nullptr, nullptr);
    agg64_kernel<<<aggGrid, blk, 0, stream>>>(xlb, xrb, rowstart, csr, att1, b1, agg, N);
    gnorm_stats_kernel<64><<<G * SPLIT, blk, 0, stream>>>(agg, goff, stats1, SPLIT);
    gnorm_finalize_kernel<64><<<G, 64, 0, stream>>>(stats1, goff, g1w, g1b, g1a, param);

    // Layer 2 (norm of layer 1 fused into GEMM staging)
    gemm2_kernel<64, true><<<(N + 63) / 64, blk, 0, stream>>>(agg, Wl2, Wr2, xlb, xrb, N, param, batch);
    agg64_kernel<<<aggGrid, blk, 0, stream>>>(xlb, xrb, rowstart, csr, att2, b2, agg, N);
    gnorm_stats_kernel<64><<<G * SPLIT, blk, 0, stream>>>(agg, goff, stats2, SPLIT);
    gnorm_finalize_kernel<64><<<G, 64, 0, stream>>>(stats2, goff, g2w, g2b, g2a, param);

    // Layer 3 (norm of layer 2 fused into GEMM staging)
    gemm2_kernel<128, true><<<(N + 31) / 32, blk, 0, stream>>>(agg, Wl3, Wr3, xlb, xrb, N, param, batch);
    agg128_mean_kernel<<<aggGrid, blk, 0, stream>>>(xlb, xrb, rowstart, csr, att3, b3, agg, N);
    gnorm_stats_kernel<32><<<G * SPLIT, blk, 0, stream>>>(agg, goff, stats3, SPLIT);
    gnorm_finalize_kernel<32><<<G, 32, 0, stream>>>(stats3, goff, g3w, g3b, g3a, param);
    pool3_kernel<<<G * SPLIT, blk, 0, stream>>>(agg, goff, param, pooled, SPLIT);
    lin_kernel<<<(G * 2 + 63) / 64, 64, 0, stream>>>(pooled, goff, Wlin, blin, outp, G);
}